// Round 1
// baseline (1039.071 us; speedup 1.0000x reference)
//
#include <hip/hip_runtime.h>
#include <cfloat>

#define N_PTS 8192
#define DTOK 256
#define KNN 16
#define NCHUNK 16
#define CHUNK 512   // N_PTS / NCHUNK

// ---------------------------------------------------------------------------
// KNN stage 1: per (i-block, j-chunk), each thread keeps a sorted top-16 of
// its point's distances within the chunk. Chunk xyz staged in LDS (broadcast
// reads). Distance arithmetic mirrors numpy: (sq_i - 2*dot) + sq_j, with
// fma-chained dot and rounded squares, to match reference tie behavior.
// ---------------------------------------------------------------------------
__global__ __launch_bounds__(256) void knn_partial_kernel(
    const float* __restrict__ xyz,
    float* __restrict__ part_d, int* __restrict__ part_i) {
  __shared__ float sx[CHUNK], sy[CHUNK], sz[CHUNK], ssq[CHUNK];
  const int t = threadIdx.x;
  const int cbase = blockIdx.y * CHUNK;

  #pragma unroll
  for (int r = 0; r < CHUNK / 256; ++r) {
    int jj = t + 256 * r;
    int j = cbase + jj;
    float x = xyz[3 * j], y = xyz[3 * j + 1], z = xyz[3 * j + 2];
    sx[jj] = x; sy[jj] = y; sz[jj] = z;
    ssq[jj] = __fadd_rn(__fadd_rn(__fmul_rn(x, x), __fmul_rn(y, y)),
                        __fmul_rn(z, z));
  }
  __syncthreads();

  const int i = blockIdx.x * 256 + t;
  const float xi = xyz[3 * i], yi = xyz[3 * i + 1], zi = xyz[3 * i + 2];
  const float sqi = __fadd_rn(__fadd_rn(__fmul_rn(xi, xi), __fmul_rn(yi, yi)),
                              __fmul_rn(zi, zi));

  float bd[KNN];
  int bx[KNN];
  #pragma unroll
  for (int s = 0; s < KNN; ++s) { bd[s] = FLT_MAX; bx[s] = 0; }

  for (int jj = 0; jj < CHUNK; ++jj) {
    float dot = fmaf(zi, sz[jj], fmaf(yi, sy[jj], __fmul_rn(xi, sx[jj])));
    float d = __fadd_rn(__fsub_rn(sqi, __fmul_rn(2.0f, dot)), ssq[jj]);
    int j = cbase + jj;
    if (j == i) d = __fadd_rn(d, 1e10f);
    if (d < bd[KNN - 1]) {                 // strict <: earlier index wins ties
      int pos = KNN - 1;
      #pragma unroll
      for (int s = KNN - 2; s >= 0; --s) {
        if (d < bd[s]) { bd[s + 1] = bd[s]; bx[s + 1] = bx[s]; pos = s; }
      }
      bd[pos] = d; bx[pos] = j;
    }
  }

  #pragma unroll
  for (int s = 0; s < KNN; ++s) {
    int slot = blockIdx.y * KNN + s;       // [chunk][slot][i] → coalesced
    part_d[slot * N_PTS + i] = bd[s];
    part_i[slot * N_PTS + i] = bx[s];
  }
}

// ---------------------------------------------------------------------------
// KNN stage 2: merge the 16 sorted partial lists (in chunk order = ascending
// index order for equal distances) into the final top-16 per point.
// ---------------------------------------------------------------------------
__global__ __launch_bounds__(256) void knn_merge_kernel(
    const float* __restrict__ part_d, const int* __restrict__ part_i,
    int* __restrict__ nbr) {
  const int i = blockIdx.x * 256 + threadIdx.x;
  float bd[KNN];
  int bx[KNN];
  #pragma unroll
  for (int s = 0; s < KNN; ++s) { bd[s] = FLT_MAX; bx[s] = 0; }

  for (int c = 0; c < NCHUNK * KNN; ++c) {
    float d = part_d[c * N_PTS + i];
    int j = part_i[c * N_PTS + i];
    if (d < bd[KNN - 1]) {
      int pos = KNN - 1;
      #pragma unroll
      for (int s = KNN - 2; s >= 0; --s) {
        if (d < bd[s]) { bd[s + 1] = bd[s]; bx[s + 1] = bx[s]; pos = s; }
      }
      bd[pos] = d; bx[pos] = j;
    }
  }
  #pragma unroll
  for (int s = 0; s < KNN; ++s) nbr[i * KNN + s] = bx[s];
}

// ---------------------------------------------------------------------------
// P/Q precompute: P = x @ W1[0:259] + b1, Q = x @ W1[259:518],
// x = concat(main[256], xyz[3]). Wave-per-4-points; x rows live in lane
// registers, broadcast to the wave via v_readlane (avoids LDS pipe).
// Lane l owns output channels {l, l+64, l+128, l+192}.
// ---------------------------------------------------------------------------
__global__ __launch_bounds__(256, 4) void pq_kernel(
    const float* __restrict__ main_in, const float* __restrict__ xyz,
    const float* __restrict__ W1, const float* __restrict__ b1,
    float* __restrict__ P, float* __restrict__ Q) {
  const int lane = threadIdx.x & 63;
  const int wave = threadIdx.x >> 6;
  const int ibase = blockIdx.x * 16 + wave * 4;

  float xr[4][5];
  #pragma unroll
  for (int m = 0; m < 4; ++m) {
    int i = ibase + m;
    #pragma unroll
    for (int q = 0; q < 4; ++q) xr[m][q] = main_in[i * DTOK + lane + 64 * q];
    xr[m][4] = (lane < 3) ? xyz[i * 3 + lane] : 0.0f;
  }

  float accP[4][4] = {}, accQ[4][4] = {};

  #pragma unroll
  for (int q = 0; q < 5; ++q) {
    const int lim = (q < 4) ? 64 : 3;
    for (int dl = 0; dl < lim; ++dl) {
      const int d = q * 64 + dl;
      const float* wt = W1 + d * DTOK + lane;
      const float* wb = W1 + (259 + d) * DTOK + lane;
      float a0 = wt[0], a1 = wt[64], a2 = wt[128], a3 = wt[192];
      float c0 = wb[0], c1 = wb[64], c2 = wb[128], c3 = wb[192];
      #pragma unroll
      for (int m = 0; m < 4; ++m) {
        float xv = __uint_as_float(
            __builtin_amdgcn_readlane(__float_as_uint(xr[m][q]), dl));
        accP[m][0] = fmaf(xv, a0, accP[m][0]);
        accP[m][1] = fmaf(xv, a1, accP[m][1]);
        accP[m][2] = fmaf(xv, a2, accP[m][2]);
        accP[m][3] = fmaf(xv, a3, accP[m][3]);
        accQ[m][0] = fmaf(xv, c0, accQ[m][0]);
        accQ[m][1] = fmaf(xv, c1, accQ[m][1]);
        accQ[m][2] = fmaf(xv, c2, accQ[m][2]);
        accQ[m][3] = fmaf(xv, c3, accQ[m][3]);
      }
    }
  }

  #pragma unroll
  for (int m = 0; m < 4; ++m) {
    int i = ibase + m;
    #pragma unroll
    for (int qq = 0; qq < 4; ++qq) {
      int c = lane + 64 * qq;
      P[i * DTOK + c] = accP[m][qq] + b1[c];
      Q[i * DTOK + c] = accQ[m][qq];
    }
  }
}

// ---------------------------------------------------------------------------
// EdgeConv core: per point i, h_k = relu(P_i + Q_{j_k} - Q_i) (k=16),
// out = max_k(h_k @ W2) + b2. Wave per point; h held in registers
// (h[k][q] = h_k[lane + 64q]), broadcast via v_readlane in the W2 dot loop.
// FMA-bound: 64 fp32 FMA + 16 readlane + 4 coalesced W2 loads per d.
// ---------------------------------------------------------------------------
__global__ __launch_bounds__(256, 2) void edge_kernel(
    const float* __restrict__ P, const float* __restrict__ Q,
    const int* __restrict__ nbr, const float* __restrict__ W2,
    const float* __restrict__ b2, float* __restrict__ out) {
  const int lane = threadIdx.x & 63;
  const int wave = threadIdx.x >> 6;
  const int i = blockIdx.x * 4 + wave;

  float pi[4], qi[4];
  #pragma unroll
  for (int q = 0; q < 4; ++q) {
    pi[q] = P[i * DTOK + lane + 64 * q];
    qi[q] = Q[i * DTOK + lane + 64 * q];
  }

  float h[KNN][4];
  #pragma unroll
  for (int k = 0; k < KNN; ++k) {
    int j = nbr[i * KNN + k];
    #pragma unroll
    for (int q = 0; q < 4; ++q) {
      float qj = Q[j * DTOK + lane + 64 * q];
      h[k][q] = fmaxf(pi[q] + (qj - qi[q]), 0.0f);
    }
  }

  float acc[KNN][4] = {};

  #pragma unroll
  for (int q = 0; q < 4; ++q) {
    for (int dl = 0; dl < 64; ++dl) {
      const float* wr = W2 + (q * 64 + dl) * DTOK + lane;
      float w0 = wr[0], w1 = wr[64], w2 = wr[128], w3 = wr[192];
      #pragma unroll
      for (int k = 0; k < KNN; ++k) {
        float hv = __uint_as_float(
            __builtin_amdgcn_readlane(__float_as_uint(h[k][q]), dl));
        acc[k][0] = fmaf(hv, w0, acc[k][0]);
        acc[k][1] = fmaf(hv, w1, acc[k][1]);
        acc[k][2] = fmaf(hv, w2, acc[k][2]);
        acc[k][3] = fmaf(hv, w3, acc[k][3]);
      }
    }
  }

  #pragma unroll
  for (int qq = 0; qq < 4; ++qq) {
    float m = acc[0][qq];
    #pragma unroll
    for (int k = 1; k < KNN; ++k) m = fmaxf(m, acc[k][qq]);
    out[i * DTOK + lane + 64 * qq] = m + b2[lane + 64 * qq];
  }
}

// ---------------------------------------------------------------------------
extern "C" void kernel_launch(void* const* d_in, const int* in_sizes, int n_in,
                              void* d_out, int out_size, void* d_ws,
                              size_t ws_size, hipStream_t stream) {
  const float* xyz = (const float*)d_in[0];
  const float* feat = (const float*)d_in[1];
  const float* W1a = (const float*)d_in[2];
  const float* b1a = (const float*)d_in[3];
  const float* W2a = (const float*)d_in[4];
  const float* b2a = (const float*)d_in[5];
  const float* W1b = (const float*)d_in[6];
  const float* b1b = (const float*)d_in[7];
  const float* W2b = (const float*)d_in[8];
  const float* b2b = (const float*)d_in[9];
  float* out = (float*)d_out;

  // ws layout (24.5 MB): nbr | bufA (part_d → P) | bufB (part_i → Q) | bufC (out_a)
  char* w = (char*)d_ws;
  const size_t SZ_NBR = (size_t)N_PTS * KNN * sizeof(int);        // 512 KB
  const size_t SZ_MAT = (size_t)N_PTS * DTOK * sizeof(float);     // 8 MB
  int* nbr = (int*)w;
  float* bufA = (float*)(w + SZ_NBR);
  float* bufB = (float*)(w + SZ_NBR + SZ_MAT);
  float* bufC = (float*)(w + SZ_NBR + 2 * SZ_MAT);

  knn_partial_kernel<<<dim3(N_PTS / 256, NCHUNK), 256, 0, stream>>>(
      xyz, bufA, (int*)bufB);
  knn_merge_kernel<<<N_PTS / 256, 256, 0, stream>>>(
      bufA, (const int*)bufB, nbr);

  // layer a: x = concat(feat, xyz)
  pq_kernel<<<N_PTS / 16, 256, 0, stream>>>(feat, xyz, W1a, b1a, bufA, bufB);
  edge_kernel<<<N_PTS / 4, 256, 0, stream>>>(bufA, bufB, nbr, W2a, b2a, bufC);

  // layer b: x = concat(out_a, xyz)
  pq_kernel<<<N_PTS / 16, 256, 0, stream>>>(bufC, xyz, W1b, b1b, bufA, bufB);
  edge_kernel<<<N_PTS / 4, 256, 0, stream>>>(bufA, bufB, nbr, W2b, b2b, out);
}

// Round 3
// 628.751 us; speedup vs baseline: 1.6526x; 1.6526x over previous
//
#include <hip/hip_runtime.h>
#include <cfloat>

#define N_PTS 8192
#define DTOK 256
#define KNN 16
#define NCHUNK 16
#define CHUNK 512   // N_PTS / NCHUNK

typedef __attribute__((ext_vector_type(8))) short short8;
typedef __attribute__((ext_vector_type(4))) float float4v;

__device__ inline short f2bf(float f) {   // RTNE fp32 -> bf16
  unsigned u = __float_as_uint(f);
  u += 0x7fffu + ((u >> 16) & 1u);
  return (short)(u >> 16);
}

// ---------------------------------------------------------------------------
// KNN stage 1 (unchanged): per (i-block, j-chunk) sorted top-16.
// ---------------------------------------------------------------------------
__global__ __launch_bounds__(256) void knn_partial_kernel(
    const float* __restrict__ xyz,
    float* __restrict__ part_d, int* __restrict__ part_i) {
  __shared__ float sx[CHUNK], sy[CHUNK], sz[CHUNK], ssq[CHUNK];
  const int t = threadIdx.x;
  const int cbase = blockIdx.y * CHUNK;

  #pragma unroll
  for (int r = 0; r < CHUNK / 256; ++r) {
    int jj = t + 256 * r;
    int j = cbase + jj;
    float x = xyz[3 * j], y = xyz[3 * j + 1], z = xyz[3 * j + 2];
    sx[jj] = x; sy[jj] = y; sz[jj] = z;
    ssq[jj] = __fadd_rn(__fadd_rn(__fmul_rn(x, x), __fmul_rn(y, y)),
                        __fmul_rn(z, z));
  }
  __syncthreads();

  const int i = blockIdx.x * 256 + t;
  const float xi = xyz[3 * i], yi = xyz[3 * i + 1], zi = xyz[3 * i + 2];
  const float sqi = __fadd_rn(__fadd_rn(__fmul_rn(xi, xi), __fmul_rn(yi, yi)),
                              __fmul_rn(zi, zi));

  float bd[KNN];
  int bx[KNN];
  #pragma unroll
  for (int s = 0; s < KNN; ++s) { bd[s] = FLT_MAX; bx[s] = 0; }

  for (int jj = 0; jj < CHUNK; ++jj) {
    float dot = fmaf(zi, sz[jj], fmaf(yi, sy[jj], __fmul_rn(xi, sx[jj])));
    float d = __fadd_rn(__fsub_rn(sqi, __fmul_rn(2.0f, dot)), ssq[jj]);
    int j = cbase + jj;
    if (j == i) d = __fadd_rn(d, 1e10f);
    if (d < bd[KNN - 1]) {
      int pos = KNN - 1;
      #pragma unroll
      for (int s = KNN - 2; s >= 0; --s) {
        if (d < bd[s]) { bd[s + 1] = bd[s]; bx[s + 1] = bx[s]; pos = s; }
      }
      bd[pos] = d; bx[pos] = j;
    }
  }

  #pragma unroll
  for (int s = 0; s < KNN; ++s) {
    int slot = blockIdx.y * KNN + s;
    part_d[slot * N_PTS + i] = bd[s];
    part_i[slot * N_PTS + i] = bx[s];
  }
}

// ---------------------------------------------------------------------------
// KNN stage 2 (unchanged).
// ---------------------------------------------------------------------------
__global__ __launch_bounds__(256) void knn_merge_kernel(
    const float* __restrict__ part_d, const int* __restrict__ part_i,
    int* __restrict__ nbr) {
  const int i = blockIdx.x * 256 + threadIdx.x;
  float bd[KNN];
  int bx[KNN];
  #pragma unroll
  for (int s = 0; s < KNN; ++s) { bd[s] = FLT_MAX; bx[s] = 0; }

  for (int c = 0; c < NCHUNK * KNN; ++c) {
    float d = part_d[c * N_PTS + i];
    int j = part_i[c * N_PTS + i];
    if (d < bd[KNN - 1]) {
      int pos = KNN - 1;
      #pragma unroll
      for (int s = KNN - 2; s >= 0; --s) {
        if (d < bd[s]) { bd[s + 1] = bd[s]; bx[s + 1] = bx[s]; pos = s; }
      }
      bd[pos] = d; bx[pos] = j;
    }
  }
  #pragma unroll
  for (int s = 0; s < KNN; ++s) nbr[i * KNN + s] = bx[s];
}

// ---------------------------------------------------------------------------
// P/Q precompute (unchanged from R2): R = P + b1 - Q, Q.
// edge h = relu(R_i + Q_j).
// ---------------------------------------------------------------------------
__global__ __launch_bounds__(256, 4) void pq_kernel(
    const float* __restrict__ main_in, const float* __restrict__ xyz,
    const float* __restrict__ W1, const float* __restrict__ b1,
    float* __restrict__ R, float* __restrict__ Q) {
  const int lane = threadIdx.x & 63;
  const int wave = threadIdx.x >> 6;
  const int ibase = blockIdx.x * 16 + wave * 4;

  float xr[4][5];
  #pragma unroll
  for (int m = 0; m < 4; ++m) {
    int i = ibase + m;
    #pragma unroll
    for (int q = 0; q < 4; ++q) xr[m][q] = main_in[i * DTOK + lane + 64 * q];
    xr[m][4] = (lane < 3) ? xyz[i * 3 + lane] : 0.0f;
  }

  float accP[4][4] = {}, accQ[4][4] = {};

  #pragma unroll
  for (int q = 0; q < 5; ++q) {
    const int lim = (q < 4) ? 64 : 3;
    for (int dl = 0; dl < lim; ++dl) {
      const int d = q * 64 + dl;
      const float* wt = W1 + d * DTOK + lane;
      const float* wb = W1 + (259 + d) * DTOK + lane;
      float a0 = wt[0], a1 = wt[64], a2 = wt[128], a3 = wt[192];
      float c0 = wb[0], c1 = wb[64], c2 = wb[128], c3 = wb[192];
      #pragma unroll
      for (int m = 0; m < 4; ++m) {
        float xv = __uint_as_float(
            __builtin_amdgcn_readlane(__float_as_uint(xr[m][q]), dl));
        accP[m][0] = fmaf(xv, a0, accP[m][0]);
        accP[m][1] = fmaf(xv, a1, accP[m][1]);
        accP[m][2] = fmaf(xv, a2, accP[m][2]);
        accP[m][3] = fmaf(xv, a3, accP[m][3]);
        accQ[m][0] = fmaf(xv, c0, accQ[m][0]);
        accQ[m][1] = fmaf(xv, c1, accQ[m][1]);
        accQ[m][2] = fmaf(xv, c2, accQ[m][2]);
        accQ[m][3] = fmaf(xv, c3, accQ[m][3]);
      }
    }
  }

  #pragma unroll
  for (int m = 0; m < 4; ++m) {
    int i = ibase + m;
    #pragma unroll
    for (int qq = 0; qq < 4; ++qq) {
      int c = lane + 64 * qq;
      R[i * DTOK + c] = (accP[m][qq] + b1[c]) - accQ[m][qq];
      Q[i * DTOK + c] = accQ[m][qq];
    }
  }
}

// ---------------------------------------------------------------------------
// EdgeConv via MFMA. Block = 4 waves, group of 8 points = 128 edge rows.
// W2 in registers as bf16 B-fragments (wave owns 64 cols). H in LDS as bf16,
// row stride 256 (64 KB exactly), with a 16 B-chunk XOR swizzle
// (phys_chunk = chunk ^ (row & 7)) to break the 512 B-row bank aliasing:
//   - A-frag ds_read_b128: 8 lanes per 4-bank group -> conflict-free.
//   - build ds_write_b64: bijection over chunks -> uniform banks.
// Row bases are multiples of 16, so row&7 == l15&7 for reads.
// mfma_f32_16x16x32_bf16: A[m=lane&15][k=quad*8+j], B[k=quad*8+j][n=lane&15],
// D row=quad*4+reg, col=lane&15. Max over 16 edge rows = max over reg +
// shfl_xor 16/32.
// ---------------------------------------------------------------------------
#define EP 8          // points per group

__global__ __launch_bounds__(256, 2) void edge_mfma_kernel(
    const float* __restrict__ R, const float* __restrict__ Q,
    const int* __restrict__ nbr, const float* __restrict__ W2,
    const float* __restrict__ b2, float* __restrict__ out,
    int num_groups, int groups_per_block) {
  __shared__ short Hs[EP * KNN * DTOK];   // 128 rows x 256, 64 KB
  const int lane = threadIdx.x & 63;
  const int wave = threadIdx.x >> 6;
  const int l15 = lane & 15;
  const int quad = lane >> 4;

  // ---- W2 -> bf16 B-fragments in registers (once per block) ----
  short8 bfr[4][8];
  #pragma unroll
  for (int nt_i = 0; nt_i < 4; ++nt_i) {
    const int n = (wave * 4 + nt_i) * 16 + l15;
    #pragma unroll
    for (int kt = 0; kt < 8; ++kt) {
      short8 f;
      #pragma unroll
      for (int jj = 0; jj < 8; ++jj) {
        int k = kt * 32 + quad * 8 + jj;
        f[jj] = f2bf(W2[k * DTOK + n]);
      }
      bfr[nt_i][kt] = f;
    }
  }

  // write-side swizzle constants (within-row 16B chunk = lane>>1)
  const int wc8 = lane >> 1;
  const int wsub = (lane & 1) * 4;

  for (int gi = 0; gi < groups_per_block; ++gi) {
    const int g = blockIdx.x + gi * gridDim.x;
    if (g >= num_groups) break;
    const int i0 = g * EP;

    // ---- build H tile: 128 rows x 256 cols, bf16, into LDS ----
    #pragma unroll 4
    for (int rr = 0; rr < 32; ++rr) {
      const int r = wave * 32 + rr;              // row in group
      const int i = i0 + (r >> 4);
      const int j = nbr[i * KNN + (r & 15)];
      const float4 qj = ((const float4*)(Q + (size_t)j * DTOK))[lane];
      const float4 ri = ((const float4*)(R + (size_t)i * DTOK))[lane];
      uint2 pk;
      pk.x = ((unsigned)(unsigned short)f2bf(fmaxf(ri.x + qj.x, 0.f))) |
             (((unsigned)(unsigned short)f2bf(fmaxf(ri.y + qj.y, 0.f))) << 16);
      pk.y = ((unsigned)(unsigned short)f2bf(fmaxf(ri.z + qj.z, 0.f))) |
             (((unsigned)(unsigned short)f2bf(fmaxf(ri.w + qj.w, 0.f))) << 16);
      *(uint2*)(&Hs[r * DTOK + ((wc8 ^ (r & 7)) << 3) + wsub]) = pk;
    }
    __syncthreads();

    // ---- GEMM + max epilogue: 4 point-pairs ----
    #pragma unroll
    for (int mp = 0; mp < 4; ++mp) {
      float4v acc[2][4];
      #pragma unroll
      for (int mi = 0; mi < 2; ++mi)
        #pragma unroll
        for (int nt_i = 0; nt_i < 4; ++nt_i)
          #pragma unroll
          for (int e = 0; e < 4; ++e) acc[mi][nt_i][e] = 0.f;

      #pragma unroll
      for (int kt = 0; kt < 8; ++kt) {
        const int pc = ((kt * 4 + quad) ^ (l15 & 7)) << 3;  // swizzled chunk
        const short8 a0 = *(const short8*)(
            &Hs[((mp * 2 + 0) * 16 + l15) * DTOK + pc]);
        const short8 a1 = *(const short8*)(
            &Hs[((mp * 2 + 1) * 16 + l15) * DTOK + pc]);
        #pragma unroll
        for (int nt_i = 0; nt_i < 4; ++nt_i) {
          acc[0][nt_i] = __builtin_amdgcn_mfma_f32_16x16x32_bf16(
              a0, bfr[nt_i][kt], acc[0][nt_i], 0, 0, 0);
          acc[1][nt_i] = __builtin_amdgcn_mfma_f32_16x16x32_bf16(
              a1, bfr[nt_i][kt], acc[1][nt_i], 0, 0, 0);
        }
      }

      #pragma unroll
      for (int mi = 0; mi < 2; ++mi) {
        #pragma unroll
        for (int nt_i = 0; nt_i < 4; ++nt_i) {
          float rm = fmaxf(fmaxf(acc[mi][nt_i][0], acc[mi][nt_i][1]),
                           fmaxf(acc[mi][nt_i][2], acc[mi][nt_i][3]));
          rm = fmaxf(rm, __shfl_xor(rm, 16, 64));
          rm = fmaxf(rm, __shfl_xor(rm, 32, 64));
          if (lane < 16) {
            const int i = i0 + mp * 2 + mi;
            const int n = (wave * 4 + nt_i) * 16 + lane;
            out[(size_t)i * DTOK + n] = rm + b2[n];
          }
        }
      }
    }
    __syncthreads();   // protect Hs before next group's build
  }
}

// ---------------------------------------------------------------------------
extern "C" void kernel_launch(void* const* d_in, const int* in_sizes, int n_in,
                              void* d_out, int out_size, void* d_ws,
                              size_t ws_size, hipStream_t stream) {
  const float* xyz = (const float*)d_in[0];
  const float* feat = (const float*)d_in[1];
  const float* W1a = (const float*)d_in[2];
  const float* b1a = (const float*)d_in[3];
  const float* W2a = (const float*)d_in[4];
  const float* b2a = (const float*)d_in[5];
  const float* W1b = (const float*)d_in[6];
  const float* b1b = (const float*)d_in[7];
  const float* W2b = (const float*)d_in[8];
  const float* b2b = (const float*)d_in[9];
  float* out = (float*)d_out;

  char* w = (char*)d_ws;
  const size_t SZ_NBR = (size_t)N_PTS * KNN * sizeof(int);        // 512 KB
  const size_t SZ_MAT = (size_t)N_PTS * DTOK * sizeof(float);     // 8 MB
  int* nbr = (int*)w;
  float* bufA = (float*)(w + SZ_NBR);          // part_d -> R
  float* bufB = (float*)(w + SZ_NBR + SZ_MAT); // part_i -> Q
  float* bufC = (float*)(w + SZ_NBR + 2 * SZ_MAT);

  knn_partial_kernel<<<dim3(N_PTS / 256, NCHUNK), 256, 0, stream>>>(
      xyz, bufA, (int*)bufB);
  knn_merge_kernel<<<N_PTS / 256, 256, 0, stream>>>(
      bufA, (const int*)bufB, nbr);

  const int num_groups = N_PTS / EP;           // 1024
  const int nblocks = 512;                     // 2 groups/block

  // layer a
  pq_kernel<<<N_PTS / 16, 256, 0, stream>>>(feat, xyz, W1a, b1a, bufA, bufB);
  edge_mfma_kernel<<<nblocks, 256, 0, stream>>>(bufA, bufB, nbr, W2a, b2a,
                                                bufC, num_groups, 2);

  // layer b
  pq_kernel<<<N_PTS / 16, 256, 0, stream>>>(bufC, xyz, W1b, b1b, bufA, bufB);
  edge_mfma_kernel<<<nblocks, 256, 0, stream>>>(bufA, bufB, nbr, W2b, b2b,
                                                out, num_groups, 2);
}

// Round 4
// 501.275 us; speedup vs baseline: 2.0729x; 1.2543x over previous
//
#include <hip/hip_runtime.h>
#include <cfloat>

#define N_PTS 8192
#define DTOK 256
#define KNN 16
#define NCHUNK 16
#define CHUNK 512   // N_PTS / NCHUNK

typedef __attribute__((ext_vector_type(8))) short short8;
typedef __attribute__((ext_vector_type(4))) float float4v;

__device__ inline short f2bf(float f) {   // RTNE fp32 -> bf16
  unsigned u = __float_as_uint(f);
  u += 0x7fffu + ((u >> 16) & 1u);
  return (short)(u >> 16);
}

// ---------------------------------------------------------------------------
// KNN stage 1, v2: deferred-insertion. Per candidate: distance + threshold
// test + exec-masked push of (d,j) into a per-lane LDS FIFO. The branchless
// 16-slot sorted insertion runs only on drain (any lane's FIFO full), so
// insert cost scales with actual inserts (~71/lane) not wave-coherent 512.
// Push order is ascending j and insertion re-checks bd[15] -> semantics
// bit-identical to the direct insertion (strict <, earlier index wins ties).
// ---------------------------------------------------------------------------
__global__ __launch_bounds__(256) void knn_partial_kernel(
    const float* __restrict__ xyz,
    float* __restrict__ part_d, int* __restrict__ part_i) {
  __shared__ float4 s4[CHUNK];        // x,y,z,sq : 8 KB
  __shared__ uint2 sbuf[KNN][256];    // FIFO [slot][tid] : 32 KB
  const int t = threadIdx.x;
  const int cbase = blockIdx.y * CHUNK;

  #pragma unroll
  for (int r = 0; r < CHUNK / 256; ++r) {
    int jj = t + 256 * r;
    int j = cbase + jj;
    float x = xyz[3 * j], y = xyz[3 * j + 1], z = xyz[3 * j + 2];
    float sq = __fadd_rn(__fadd_rn(__fmul_rn(x, x), __fmul_rn(y, y)),
                         __fmul_rn(z, z));
    s4[jj] = make_float4(x, y, z, sq);
  }
  __syncthreads();

  const int i = blockIdx.x * 256 + t;
  const float xi = xyz[3 * i], yi = xyz[3 * i + 1], zi = xyz[3 * i + 2];
  const float sqi = __fadd_rn(__fadd_rn(__fmul_rn(xi, xi), __fmul_rn(yi, yi)),
                              __fmul_rn(zi, zi));

  float bd[KNN];
  int bx[KNN];
  #pragma unroll
  for (int s = 0; s < KNN; ++s) { bd[s] = FLT_MAX; bx[s] = 0; }
  int cnt = 0;

  auto drain = [&]() {
    int tt = 0;
    while (__any(tt < cnt)) {
      float d = FLT_MAX;
      int j = 0;
      if (tt < cnt) {
        uint2 e = sbuf[tt][t];
        d = __uint_as_float(e.x);
        j = (int)e.y;
      }
      bool c[KNN];
      #pragma unroll
      for (int s = 0; s < KNN; ++s) c[s] = d < bd[s];
      #pragma unroll
      for (int s = KNN - 1; s >= 1; --s) {
        bd[s] = c[s - 1] ? bd[s - 1] : (c[s] ? d : bd[s]);
        bx[s] = c[s - 1] ? bx[s - 1] : (c[s] ? j : bx[s]);
      }
      bd[0] = c[0] ? d : bd[0];
      bx[0] = c[0] ? j : bx[0];
      ++tt;
    }
    cnt = 0;
  };

  for (int jj = 0; jj < CHUNK; ++jj) {
    float4 p = s4[jj];
    float dot = fmaf(zi, p.z, fmaf(yi, p.y, __fmul_rn(xi, p.x)));
    float d = __fadd_rn(__fsub_rn(sqi, __fmul_rn(2.0f, dot)), p.w);
    int j = cbase + jj;
    if (j == i) d = __fadd_rn(d, 1e10f);
    if (d < bd[KNN - 1]) {
      sbuf[cnt][t] = make_uint2(__float_as_uint(d), (unsigned)j);
      ++cnt;
    }
    if (__any(cnt == KNN)) drain();
  }
  drain();

  #pragma unroll
  for (int s = 0; s < KNN; ++s) {
    int slot = blockIdx.y * KNN + s;
    part_d[slot * N_PTS + i] = bd[s];
    part_i[slot * N_PTS + i] = bx[s];
  }
}

// ---------------------------------------------------------------------------
// KNN stage 2 (unchanged).
// ---------------------------------------------------------------------------
__global__ __launch_bounds__(256) void knn_merge_kernel(
    const float* __restrict__ part_d, const int* __restrict__ part_i,
    int* __restrict__ nbr) {
  const int i = blockIdx.x * 256 + threadIdx.x;
  float bd[KNN];
  int bx[KNN];
  #pragma unroll
  for (int s = 0; s < KNN; ++s) { bd[s] = FLT_MAX; bx[s] = 0; }

  for (int c = 0; c < NCHUNK * KNN; ++c) {
    float d = part_d[c * N_PTS + i];
    int j = part_i[c * N_PTS + i];
    if (d < bd[KNN - 1]) {
      int pos = KNN - 1;
      #pragma unroll
      for (int s = KNN - 2; s >= 0; --s) {
        if (d < bd[s]) { bd[s + 1] = bd[s]; bx[s + 1] = bx[s]; pos = s; }
      }
      bd[pos] = d; bx[pos] = j;
    }
  }
  #pragma unroll
  for (int s = 0; s < KNN; ++s) nbr[i * KNN + s] = bx[s];
}

// ---------------------------------------------------------------------------
// P/Q precompute (unchanged): R = P + b1 - Q, Q.  edge h = relu(R_i + Q_j).
// ---------------------------------------------------------------------------
__global__ __launch_bounds__(256, 4) void pq_kernel(
    const float* __restrict__ main_in, const float* __restrict__ xyz,
    const float* __restrict__ W1, const float* __restrict__ b1,
    float* __restrict__ R, float* __restrict__ Q) {
  const int lane = threadIdx.x & 63;
  const int wave = threadIdx.x >> 6;
  const int ibase = blockIdx.x * 16 + wave * 4;

  float xr[4][5];
  #pragma unroll
  for (int m = 0; m < 4; ++m) {
    int i = ibase + m;
    #pragma unroll
    for (int q = 0; q < 4; ++q) xr[m][q] = main_in[i * DTOK + lane + 64 * q];
    xr[m][4] = (lane < 3) ? xyz[i * 3 + lane] : 0.0f;
  }

  float accP[4][4] = {}, accQ[4][4] = {};

  #pragma unroll
  for (int q = 0; q < 5; ++q) {
    const int lim = (q < 4) ? 64 : 3;
    for (int dl = 0; dl < lim; ++dl) {
      const int d = q * 64 + dl;
      const float* wt = W1 + d * DTOK + lane;
      const float* wb = W1 + (259 + d) * DTOK + lane;
      float a0 = wt[0], a1 = wt[64], a2 = wt[128], a3 = wt[192];
      float c0 = wb[0], c1 = wb[64], c2 = wb[128], c3 = wb[192];
      #pragma unroll
      for (int m = 0; m < 4; ++m) {
        float xv = __uint_as_float(
            __builtin_amdgcn_readlane(__float_as_uint(xr[m][q]), dl));
        accP[m][0] = fmaf(xv, a0, accP[m][0]);
        accP[m][1] = fmaf(xv, a1, accP[m][1]);
        accP[m][2] = fmaf(xv, a2, accP[m][2]);
        accP[m][3] = fmaf(xv, a3, accP[m][3]);
        accQ[m][0] = fmaf(xv, c0, accQ[m][0]);
        accQ[m][1] = fmaf(xv, c1, accQ[m][1]);
        accQ[m][2] = fmaf(xv, c2, accQ[m][2]);
        accQ[m][3] = fmaf(xv, c3, accQ[m][3]);
      }
    }
  }

  #pragma unroll
  for (int m = 0; m < 4; ++m) {
    int i = ibase + m;
    #pragma unroll
    for (int qq = 0; qq < 4; ++qq) {
      int c = lane + 64 * qq;
      R[i * DTOK + c] = (accP[m][qq] + b1[c]) - accQ[m][qq];
      Q[i * DTOK + c] = accQ[m][qq];
    }
  }
}

// ---------------------------------------------------------------------------
// EdgeConv via MFMA (unchanged from R3).
// ---------------------------------------------------------------------------
#define EP 8          // points per group

__global__ __launch_bounds__(256, 2) void edge_mfma_kernel(
    const float* __restrict__ R, const float* __restrict__ Q,
    const int* __restrict__ nbr, const float* __restrict__ W2,
    const float* __restrict__ b2, float* __restrict__ out,
    int num_groups, int groups_per_block) {
  __shared__ short Hs[EP * KNN * DTOK];   // 128 rows x 256, 64 KB
  const int lane = threadIdx.x & 63;
  const int wave = threadIdx.x >> 6;
  const int l15 = lane & 15;
  const int quad = lane >> 4;

  short8 bfr[4][8];
  #pragma unroll
  for (int nt_i = 0; nt_i < 4; ++nt_i) {
    const int n = (wave * 4 + nt_i) * 16 + l15;
    #pragma unroll
    for (int kt = 0; kt < 8; ++kt) {
      short8 f;
      #pragma unroll
      for (int jj = 0; jj < 8; ++jj) {
        int k = kt * 32 + quad * 8 + jj;
        f[jj] = f2bf(W2[k * DTOK + n]);
      }
      bfr[nt_i][kt] = f;
    }
  }

  const int wc8 = lane >> 1;
  const int wsub = (lane & 1) * 4;

  for (int gi = 0; gi < groups_per_block; ++gi) {
    const int g = blockIdx.x + gi * gridDim.x;
    if (g >= num_groups) break;
    const int i0 = g * EP;

    #pragma unroll 4
    for (int rr = 0; rr < 32; ++rr) {
      const int r = wave * 32 + rr;
      const int i = i0 + (r >> 4);
      const int j = nbr[i * KNN + (r & 15)];
      const float4 qj = ((const float4*)(Q + (size_t)j * DTOK))[lane];
      const float4 ri = ((const float4*)(R + (size_t)i * DTOK))[lane];
      uint2 pk;
      pk.x = ((unsigned)(unsigned short)f2bf(fmaxf(ri.x + qj.x, 0.f))) |
             (((unsigned)(unsigned short)f2bf(fmaxf(ri.y + qj.y, 0.f))) << 16);
      pk.y = ((unsigned)(unsigned short)f2bf(fmaxf(ri.z + qj.z, 0.f))) |
             (((unsigned)(unsigned short)f2bf(fmaxf(ri.w + qj.w, 0.f))) << 16);
      *(uint2*)(&Hs[r * DTOK + ((wc8 ^ (r & 7)) << 3) + wsub]) = pk;
    }
    __syncthreads();

    #pragma unroll
    for (int mp = 0; mp < 4; ++mp) {
      float4v acc[2][4];
      #pragma unroll
      for (int mi = 0; mi < 2; ++mi)
        #pragma unroll
        for (int nt_i = 0; nt_i < 4; ++nt_i)
          #pragma unroll
          for (int e = 0; e < 4; ++e) acc[mi][nt_i][e] = 0.f;

      #pragma unroll
      for (int kt = 0; kt < 8; ++kt) {
        const int pc = ((kt * 4 + quad) ^ (l15 & 7)) << 3;
        const short8 a0 = *(const short8*)(
            &Hs[((mp * 2 + 0) * 16 + l15) * DTOK + pc]);
        const short8 a1 = *(const short8*)(
            &Hs[((mp * 2 + 1) * 16 + l15) * DTOK + pc]);
        #pragma unroll
        for (int nt_i = 0; nt_i < 4; ++nt_i) {
          acc[0][nt_i] = __builtin_amdgcn_mfma_f32_16x16x32_bf16(
              a0, bfr[nt_i][kt], acc[0][nt_i], 0, 0, 0);
          acc[1][nt_i] = __builtin_amdgcn_mfma_f32_16x16x32_bf16(
              a1, bfr[nt_i][kt], acc[1][nt_i], 0, 0, 0);
        }
      }

      #pragma unroll
      for (int mi = 0; mi < 2; ++mi) {
        #pragma unroll
        for (int nt_i = 0; nt_i < 4; ++nt_i) {
          float rm = fmaxf(fmaxf(acc[mi][nt_i][0], acc[mi][nt_i][1]),
                           fmaxf(acc[mi][nt_i][2], acc[mi][nt_i][3]));
          rm = fmaxf(rm, __shfl_xor(rm, 16, 64));
          rm = fmaxf(rm, __shfl_xor(rm, 32, 64));
          if (lane < 16) {
            const int i = i0 + mp * 2 + mi;
            const int n = (wave * 4 + nt_i) * 16 + lane;
            out[(size_t)i * DTOK + n] = rm + b2[n];
          }
        }
      }
    }
    __syncthreads();
  }
}

// ---------------------------------------------------------------------------
extern "C" void kernel_launch(void* const* d_in, const int* in_sizes, int n_in,
                              void* d_out, int out_size, void* d_ws,
                              size_t ws_size, hipStream_t stream) {
  const float* xyz = (const float*)d_in[0];
  const float* feat = (const float*)d_in[1];
  const float* W1a = (const float*)d_in[2];
  const float* b1a = (const float*)d_in[3];
  const float* W2a = (const float*)d_in[4];
  const float* b2a = (const float*)d_in[5];
  const float* W1b = (const float*)d_in[6];
  const float* b1b = (const float*)d_in[7];
  const float* W2b = (const float*)d_in[8];
  const float* b2b = (const float*)d_in[9];
  float* out = (float*)d_out;

  char* w = (char*)d_ws;
  const size_t SZ_NBR = (size_t)N_PTS * KNN * sizeof(int);        // 512 KB
  const size_t SZ_MAT = (size_t)N_PTS * DTOK * sizeof(float);     // 8 MB
  int* nbr = (int*)w;
  float* bufA = (float*)(w + SZ_NBR);          // part_d -> R
  float* bufB = (float*)(w + SZ_NBR + SZ_MAT); // part_i -> Q
  float* bufC = (float*)(w + SZ_NBR + 2 * SZ_MAT);

  knn_partial_kernel<<<dim3(N_PTS / 256, NCHUNK), 256, 0, stream>>>(
      xyz, bufA, (int*)bufB);
  knn_merge_kernel<<<N_PTS / 256, 256, 0, stream>>>(
      bufA, (const int*)bufB, nbr);

  const int num_groups = N_PTS / EP;           // 1024
  const int nblocks = 512;                     // 2 groups/block

  // layer a
  pq_kernel<<<N_PTS / 16, 256, 0, stream>>>(feat, xyz, W1a, b1a, bufA, bufB);
  edge_mfma_kernel<<<nblocks, 256, 0, stream>>>(bufA, bufB, nbr, W2a, b2a,
                                                bufC, num_groups, 2);

  // layer b
  pq_kernel<<<N_PTS / 16, 256, 0, stream>>>(bufC, xyz, W1b, b1b, bufA, bufB);
  edge_mfma_kernel<<<nblocks, 256, 0, stream>>>(bufA, bufB, nbr, W2b, b2b,
                                                out, num_groups, 2);
}

// Round 5
// 384.221 us; speedup vs baseline: 2.7044x; 1.3047x over previous
//
#include <hip/hip_runtime.h>
#include <cfloat>

#define N_PTS 8192
#define DTOK 256
#define KNN 16
#define NCHUNK 16
#define CHUNK 512   // N_PTS / NCHUNK

typedef __attribute__((ext_vector_type(8))) short short8;
typedef __attribute__((ext_vector_type(4))) float float4v;

__device__ inline short f2bf(float f) {   // RTNE fp32 -> bf16
  unsigned u = __float_as_uint(f);
  u += 0x7fffu + ((u >> 16) & 1u);
  return (short)(u >> 16);
}

// ---------------------------------------------------------------------------
// KNN stage 1 (deferred-insertion FIFO, as R4). Output now packed uint2
// (d_bits, j) per slot -> one coalesced 8 B store per slot, and stage 2 needs
// a single load per entry.
// ---------------------------------------------------------------------------
__global__ __launch_bounds__(256) void knn_partial_kernel(
    const float* __restrict__ xyz, uint2* __restrict__ part) {
  __shared__ float4 s4[CHUNK];        // x,y,z,sq : 8 KB
  __shared__ uint2 sbuf[KNN][256];    // FIFO [slot][tid] : 32 KB
  const int t = threadIdx.x;
  const int cbase = blockIdx.y * CHUNK;

  #pragma unroll
  for (int r = 0; r < CHUNK / 256; ++r) {
    int jj = t + 256 * r;
    int j = cbase + jj;
    float x = xyz[3 * j], y = xyz[3 * j + 1], z = xyz[3 * j + 2];
    float sq = __fadd_rn(__fadd_rn(__fmul_rn(x, x), __fmul_rn(y, y)),
                         __fmul_rn(z, z));
    s4[jj] = make_float4(x, y, z, sq);
  }
  __syncthreads();

  const int i = blockIdx.x * 256 + t;
  const float xi = xyz[3 * i], yi = xyz[3 * i + 1], zi = xyz[3 * i + 2];
  const float sqi = __fadd_rn(__fadd_rn(__fmul_rn(xi, xi), __fmul_rn(yi, yi)),
                              __fmul_rn(zi, zi));

  float bd[KNN];
  int bx[KNN];
  #pragma unroll
  for (int s = 0; s < KNN; ++s) { bd[s] = FLT_MAX; bx[s] = 0; }
  int cnt = 0;

  auto drain = [&]() {
    int tt = 0;
    while (__any(tt < cnt)) {
      float d = FLT_MAX;
      int j = 0;
      if (tt < cnt) {
        uint2 e = sbuf[tt][t];
        d = __uint_as_float(e.x);
        j = (int)e.y;
      }
      bool c[KNN];
      #pragma unroll
      for (int s = 0; s < KNN; ++s) c[s] = d < bd[s];
      #pragma unroll
      for (int s = KNN - 1; s >= 1; --s) {
        bd[s] = c[s - 1] ? bd[s - 1] : (c[s] ? d : bd[s]);
        bx[s] = c[s - 1] ? bx[s - 1] : (c[s] ? j : bx[s]);
      }
      bd[0] = c[0] ? d : bd[0];
      bx[0] = c[0] ? j : bx[0];
      ++tt;
    }
    cnt = 0;
  };

  for (int jj = 0; jj < CHUNK; ++jj) {
    float4 p = s4[jj];
    float dot = fmaf(zi, p.z, fmaf(yi, p.y, __fmul_rn(xi, p.x)));
    float d = __fadd_rn(__fsub_rn(sqi, __fmul_rn(2.0f, dot)), p.w);
    int j = cbase + jj;
    if (j == i) d = __fadd_rn(d, 1e10f);
    if (d < bd[KNN - 1]) {
      sbuf[cnt][t] = make_uint2(__float_as_uint(d), (unsigned)j);
      ++cnt;
    }
    if (__any(cnt == KNN)) drain();
  }
  drain();

  #pragma unroll
  for (int s = 0; s < KNN; ++s) {
    int slot = blockIdx.y * KNN + s;
    part[(size_t)slot * N_PTS + i] =
        make_uint2(__float_as_uint(bd[s]), (unsigned)bx[s]);
  }
}

// ---------------------------------------------------------------------------
// KNN stage 2, v2: 16-lane tournament merge of 16 sorted lists per point.
// Lane l of a 16-lane group holds chunk l's list (head in regs, rest in its
// own LDS column -> no barriers). 16 rounds of butterfly argmin(d, tie: low
// chunk) + broadcast + winner head-advance. Chunk order == ascending-j order,
// so tie semantics match the serial stable insertion exactly.
// ---------------------------------------------------------------------------
__global__ __launch_bounds__(256) void knn_merge_kernel(
    const uint2* __restrict__ part, int* __restrict__ nbr) {
  __shared__ uint2 sl[KNN * 256];     // [slot][tid] : 32 KB
  const int t = threadIdx.x;
  const int c = t & 15;               // chunk this lane owns
  const int i = blockIdx.x * 16 + (t >> 4);

  float hd;  int hj;
  {
    uint2 e0 = part[(size_t)(c * KNN) * N_PTS + i];
    hd = __uint_as_float(e0.x);
    hj = (int)e0.y;
    #pragma unroll
    for (int s = 1; s < KNN; ++s)
      sl[s * 256 + t] = part[(size_t)(c * KNN + s) * N_PTS + i];
  }

  int idx = 1;
  int outj = 0;
  #pragma unroll
  for (int r = 0; r < KNN; ++r) {
    float md = hd;  int mc = c;
    #pragma unroll
    for (int m = 1; m < 16; m <<= 1) {
      float od = __shfl_xor(md, m, 16);
      int oc = __shfl_xor(mc, m, 16);
      bool take = (od < md) || (od == md && oc < mc);
      md = take ? od : md;
      mc = take ? oc : mc;
    }
    int jw = __shfl(hj, mc, 16);      // winner's j, before advance
    if (c == r) outj = jw;            // lane r captures output slot r
    if (c == mc) {                    // winner advances its head
      if (idx < KNN) {
        uint2 e = sl[idx * 256 + t];
        hd = __uint_as_float(e.x);
        hj = (int)e.y;
      } else {
        hd = FLT_MAX;  hj = 0;
      }
      ++idx;
    }
  }
  nbr[i * KNN + c] = outj;
}

// ---------------------------------------------------------------------------
// P/Q precompute (unchanged): R = P + b1 - Q, Q.  edge h = relu(R_i + Q_j).
// ---------------------------------------------------------------------------
__global__ __launch_bounds__(256, 4) void pq_kernel(
    const float* __restrict__ main_in, const float* __restrict__ xyz,
    const float* __restrict__ W1, const float* __restrict__ b1,
    float* __restrict__ R, float* __restrict__ Q) {
  const int lane = threadIdx.x & 63;
  const int wave = threadIdx.x >> 6;
  const int ibase = blockIdx.x * 16 + wave * 4;

  float xr[4][5];
  #pragma unroll
  for (int m = 0; m < 4; ++m) {
    int i = ibase + m;
    #pragma unroll
    for (int q = 0; q < 4; ++q) xr[m][q] = main_in[i * DTOK + lane + 64 * q];
    xr[m][4] = (lane < 3) ? xyz[i * 3 + lane] : 0.0f;
  }

  float accP[4][4] = {}, accQ[4][4] = {};

  #pragma unroll
  for (int q = 0; q < 5; ++q) {
    const int lim = (q < 4) ? 64 : 3;
    for (int dl = 0; dl < lim; ++dl) {
      const int d = q * 64 + dl;
      const float* wt = W1 + d * DTOK + lane;
      const float* wb = W1 + (259 + d) * DTOK + lane;
      float a0 = wt[0], a1 = wt[64], a2 = wt[128], a3 = wt[192];
      float c0 = wb[0], c1 = wb[64], c2 = wb[128], c3 = wb[192];
      #pragma unroll
      for (int m = 0; m < 4; ++m) {
        float xv = __uint_as_float(
            __builtin_amdgcn_readlane(__float_as_uint(xr[m][q]), dl));
        accP[m][0] = fmaf(xv, a0, accP[m][0]);
        accP[m][1] = fmaf(xv, a1, accP[m][1]);
        accP[m][2] = fmaf(xv, a2, accP[m][2]);
        accP[m][3] = fmaf(xv, a3, accP[m][3]);
        accQ[m][0] = fmaf(xv, c0, accQ[m][0]);
        accQ[m][1] = fmaf(xv, c1, accQ[m][1]);
        accQ[m][2] = fmaf(xv, c2, accQ[m][2]);
        accQ[m][3] = fmaf(xv, c3, accQ[m][3]);
      }
    }
  }

  #pragma unroll
  for (int m = 0; m < 4; ++m) {
    int i = ibase + m;
    #pragma unroll
    for (int qq = 0; qq < 4; ++qq) {
      int c = lane + 64 * qq;
      R[i * DTOK + c] = (accP[m][qq] + b1[c]) - accQ[m][qq];
      Q[i * DTOK + c] = accQ[m][qq];
    }
  }
}

// ---------------------------------------------------------------------------
// EdgeConv via MFMA (unchanged from R3).
// ---------------------------------------------------------------------------
#define EP 8          // points per group

__global__ __launch_bounds__(256, 2) void edge_mfma_kernel(
    const float* __restrict__ R, const float* __restrict__ Q,
    const int* __restrict__ nbr, const float* __restrict__ W2,
    const float* __restrict__ b2, float* __restrict__ out,
    int num_groups, int groups_per_block) {
  __shared__ short Hs[EP * KNN * DTOK];   // 128 rows x 256, 64 KB
  const int lane = threadIdx.x & 63;
  const int wave = threadIdx.x >> 6;
  const int l15 = lane & 15;
  const int quad = lane >> 4;

  short8 bfr[4][8];
  #pragma unroll
  for (int nt_i = 0; nt_i < 4; ++nt_i) {
    const int n = (wave * 4 + nt_i) * 16 + l15;
    #pragma unroll
    for (int kt = 0; kt < 8; ++kt) {
      short8 f;
      #pragma unroll
      for (int jj = 0; jj < 8; ++jj) {
        int k = kt * 32 + quad * 8 + jj;
        f[jj] = f2bf(W2[k * DTOK + n]);
      }
      bfr[nt_i][kt] = f;
    }
  }

  const int wc8 = lane >> 1;
  const int wsub = (lane & 1) * 4;

  for (int gi = 0; gi < groups_per_block; ++gi) {
    const int g = blockIdx.x + gi * gridDim.x;
    if (g >= num_groups) break;
    const int i0 = g * EP;

    #pragma unroll 4
    for (int rr = 0; rr < 32; ++rr) {
      const int r = wave * 32 + rr;
      const int i = i0 + (r >> 4);
      const int j = nbr[i * KNN + (r & 15)];
      const float4 qj = ((const float4*)(Q + (size_t)j * DTOK))[lane];
      const float4 ri = ((const float4*)(R + (size_t)i * DTOK))[lane];
      uint2 pk;
      pk.x = ((unsigned)(unsigned short)f2bf(fmaxf(ri.x + qj.x, 0.f))) |
             (((unsigned)(unsigned short)f2bf(fmaxf(ri.y + qj.y, 0.f))) << 16);
      pk.y = ((unsigned)(unsigned short)f2bf(fmaxf(ri.z + qj.z, 0.f))) |
             (((unsigned)(unsigned short)f2bf(fmaxf(ri.w + qj.w, 0.f))) << 16);
      *(uint2*)(&Hs[r * DTOK + ((wc8 ^ (r & 7)) << 3) + wsub]) = pk;
    }
    __syncthreads();

    #pragma unroll
    for (int mp = 0; mp < 4; ++mp) {
      float4v acc[2][4];
      #pragma unroll
      for (int mi = 0; mi < 2; ++mi)
        #pragma unroll
        for (int nt_i = 0; nt_i < 4; ++nt_i)
          #pragma unroll
          for (int e = 0; e < 4; ++e) acc[mi][nt_i][e] = 0.f;

      #pragma unroll
      for (int kt = 0; kt < 8; ++kt) {
        const int pc = ((kt * 4 + quad) ^ (l15 & 7)) << 3;
        const short8 a0 = *(const short8*)(
            &Hs[((mp * 2 + 0) * 16 + l15) * DTOK + pc]);
        const short8 a1 = *(const short8*)(
            &Hs[((mp * 2 + 1) * 16 + l15) * DTOK + pc]);
        #pragma unroll
        for (int nt_i = 0; nt_i < 4; ++nt_i) {
          acc[0][nt_i] = __builtin_amdgcn_mfma_f32_16x16x32_bf16(
              a0, bfr[nt_i][kt], acc[0][nt_i], 0, 0, 0);
          acc[1][nt_i] = __builtin_amdgcn_mfma_f32_16x16x32_bf16(
              a1, bfr[nt_i][kt], acc[1][nt_i], 0, 0, 0);
        }
      }

      #pragma unroll
      for (int mi = 0; mi < 2; ++mi) {
        #pragma unroll
        for (int nt_i = 0; nt_i < 4; ++nt_i) {
          float rm = fmaxf(fmaxf(acc[mi][nt_i][0], acc[mi][nt_i][1]),
                           fmaxf(acc[mi][nt_i][2], acc[mi][nt_i][3]));
          rm = fmaxf(rm, __shfl_xor(rm, 16, 64));
          rm = fmaxf(rm, __shfl_xor(rm, 32, 64));
          if (lane < 16) {
            const int i = i0 + mp * 2 + mi;
            const int n = (wave * 4 + nt_i) * 16 + lane;
            out[(size_t)i * DTOK + n] = rm + b2[n];
          }
        }
      }
    }
    __syncthreads();
  }
}

// ---------------------------------------------------------------------------
extern "C" void kernel_launch(void* const* d_in, const int* in_sizes, int n_in,
                              void* d_out, int out_size, void* d_ws,
                              size_t ws_size, hipStream_t stream) {
  const float* xyz = (const float*)d_in[0];
  const float* feat = (const float*)d_in[1];
  const float* W1a = (const float*)d_in[2];
  const float* b1a = (const float*)d_in[3];
  const float* W2a = (const float*)d_in[4];
  const float* b2a = (const float*)d_in[5];
  const float* W1b = (const float*)d_in[6];
  const float* b1b = (const float*)d_in[7];
  const float* W2b = (const float*)d_in[8];
  const float* b2b = (const float*)d_in[9];
  float* out = (float*)d_out;

  char* w = (char*)d_ws;
  const size_t SZ_NBR = (size_t)N_PTS * KNN * sizeof(int);        // 512 KB
  const size_t SZ_MAT = (size_t)N_PTS * DTOK * sizeof(float);     // 8 MB
  int* nbr = (int*)w;
  uint2* part = (uint2*)(w + SZ_NBR);          // 16 MB (spans bufA+bufB)
  float* bufA = (float*)(w + SZ_NBR);          // later: R
  float* bufB = (float*)(w + SZ_NBR + SZ_MAT); // later: Q
  float* bufC = (float*)(w + SZ_NBR + 2 * SZ_MAT);

  knn_partial_kernel<<<dim3(N_PTS / 256, NCHUNK), 256, 0, stream>>>(xyz, part);
  knn_merge_kernel<<<N_PTS / 16, 256, 0, stream>>>(part, nbr);

  const int num_groups = N_PTS / EP;           // 1024
  const int nblocks = 512;                     // 2 groups/block

  // layer a
  pq_kernel<<<N_PTS / 16, 256, 0, stream>>>(feat, xyz, W1a, b1a, bufA, bufB);
  edge_mfma_kernel<<<nblocks, 256, 0, stream>>>(bufA, bufB, nbr, W2a, b2a,
                                                bufC, num_groups, 2);

  // layer b
  pq_kernel<<<N_PTS / 16, 256, 0, stream>>>(bufC, xyz, W1b, b1b, bufA, bufB);
  edge_mfma_kernel<<<nblocks, 256, 0, stream>>>(bufA, bufB, nbr, W2b, b2b,
                                                out, num_groups, 2);
}